// Round 1
// baseline (243.408 us; speedup 1.0000x reference)
//
#include <hip/hip_runtime.h>
#include <cmath>

namespace {

constexpr int Bn = 4;
constexpr int Cn = 3;
constexpr int Hn = 32, Wn = 32, Dn = 32;
constexpr int Kn = 16;
constexpr int Sn = 16;
constexpr int HOn = 30;
constexpr int Pn = HOn * HOn * HOn;       // 27000
constexpr int XCH = Hn * Wn * Dn;          // 32768 (one channel)
constexpr int XB  = Cn * XCH;              // 98304 (one batch)

__device__ __constant__ float kMops[16][4] = {
    {0, 0, 0, 0},  {0, 0, 0, 1},  {0, 1, 0, -1}, {0, 1, 0, 0},
    {0, 0, 1, -1}, {0, 0, 1, 0},  {0, 1, 1, -2}, {0, 1, 1, -1},
    {1, -1, -1, 1},{1, -1, -1, 2},{1, 0, -1, 0}, {1, 0, -1, 1},
    {1, -1, 0, 0}, {1, -1, 0, 1}, {1, 0, 0, -1}, {1, 0, 0, 0}};

__device__ __forceinline__ float binop(float a, float b, const float* c) {
    return c[0] + c[1] * a + c[2] * b + c[3] * (a * b);
}

__global__ __launch_bounds__(256)
void logic_conv3d(const float* __restrict__ x,
                  const int* __restrict__ idx_a,
                  const int* __restrict__ idx_b,
                  const float* __restrict__ w0,
                  const float* __restrict__ w1,
                  const float* __restrict__ w2,
                  const float* __restrict__ w3,
                  const float* __restrict__ w4,
                  float* __restrict__ out) {
    const int k = blockIdx.y;
    const int tid = threadIdx.x;

    // 31 coefficient rows: lvl0 n=0..15 -> rows 0..15, lvl1 -> 16..23,
    // lvl2 -> 24..27, lvl3 -> 28..29, lvl4 -> 30.
    __shared__ float coef[31][4];
    __shared__ int base_a[Sn], base_b[Sn];

    // idx_a[k, p=0, s, :] == pa[k, s] because off[0] == (0,0,0,0) (PAD=0).
    if (tid < Sn) {
        const int* pa = idx_a + (((size_t)k * Pn) * Sn + tid) * 4;
        base_a[tid] = pa[3] * XCH + pa[0] * (Wn * Dn) + pa[1] * Dn + pa[2];
        const int* pb = idx_b + (((size_t)k * Pn) * Sn + tid) * 4;
        base_b[tid] = pb[3] * XCH + pb[0] * (Wn * Dn) + pb[1] * Dn + pb[2];
    }
    if (tid < 31) {
        const float* wl;
        int n;
        if (tid < 16)      { wl = w0; n = tid; }
        else if (tid < 24) { wl = w1; n = tid - 16; }
        else if (tid < 28) { wl = w2; n = tid - 24; }
        else if (tid < 30) { wl = w3; n = tid - 28; }
        else               { wl = w4; n = 0; }
        const float* row = wl + (n * Kn + k) * 16;  // w_l[n, k, :]
        float e[16];
        float mx = row[0];
        #pragma unroll
        for (int o = 1; o < 16; ++o) mx = fmaxf(mx, row[o]);
        float sum = 0.f;
        #pragma unroll
        for (int o = 0; o < 16; ++o) { e[o] = expf(row[o] - mx); sum += e[o]; }
        const float inv = 1.0f / sum;
        #pragma unroll
        for (int c = 0; c < 4; ++c) {
            float acc = 0.f;
            #pragma unroll
            for (int o = 0; o < 16; ++o) acc += e[o] * kMops[o][c];
            coef[tid][c] = acc * inv;
        }
    }
    __syncthreads();

    const int p = blockIdx.x * blockDim.x + tid;
    if (p >= Pn) return;

    // p = h0*900 + w0*30 + d0  (meshgrid 'ij', d fastest)
    const int h0 = p / 900;
    const int rem = p - h0 * 900;
    const int w0i = rem / 30;
    const int d0 = rem - w0i * 30;
    const int poff = h0 * (Wn * Dn) + w0i * Dn + d0;

    int offa[Sn], offb[Sn];
    #pragma unroll
    for (int s = 0; s < Sn; ++s) {
        offa[s] = base_a[s] + poff;
        offb[s] = base_b[s] + poff;
    }

    for (int b = 0; b < Bn; ++b) {
        const float* xb = x + (size_t)b * XB;
        float v[16];
        #pragma unroll
        for (int s = 0; s < 16; ++s) {
            const float a = xb[offa[s]];
            const float bb = xb[offb[s]];
            v[s] = binop(a, bb, coef[s]);
        }
        #pragma unroll
        for (int n = 0; n < 8; ++n) v[n] = binop(v[2 * n], v[2 * n + 1], coef[16 + n]);
        #pragma unroll
        for (int n = 0; n < 4; ++n) v[n] = binop(v[2 * n], v[2 * n + 1], coef[24 + n]);
        #pragma unroll
        for (int n = 0; n < 2; ++n) v[n] = binop(v[2 * n], v[2 * n + 1], coef[28 + n]);
        const float res = binop(v[0], v[1], coef[30]);
        out[((size_t)b * Kn + k) * Pn + p] = res;
    }
}

}  // namespace

extern "C" void kernel_launch(void* const* d_in, const int* in_sizes, int n_in,
                              void* d_out, int out_size, void* d_ws, size_t ws_size,
                              hipStream_t stream) {
    const float* x     = (const float*)d_in[0];
    const int*   idx_a = (const int*)d_in[1];
    const int*   idx_b = (const int*)d_in[2];
    const float* w0    = (const float*)d_in[3];
    const float* w1    = (const float*)d_in[4];
    const float* w2    = (const float*)d_in[5];
    const float* w3    = (const float*)d_in[6];
    const float* w4    = (const float*)d_in[7];
    float* out = (float*)d_out;

    dim3 grid((Pn + 255) / 256, Kn);
    hipLaunchKernelGGL(logic_conv3d, grid, dim3(256), 0, stream,
                       x, idx_a, idx_b, w0, w1, w2, w3, w4, out);
}

// Round 2
// 208.452 us; speedup vs baseline: 1.1677x; 1.1677x over previous
//
#include <hip/hip_runtime.h>
#include <cmath>

namespace {

constexpr int Bn = 4;
constexpr int Cn = 3;
constexpr int Hn = 32, Wn = 32, Dn = 32;
constexpr int Kn = 16;
constexpr int Sn = 16;
constexpr int HOn = 30;
constexpr int Pn = HOn * HOn * HOn;       // 27000
constexpr int XCH = Hn * Wn * Dn;          // 32768 (one channel)
constexpr int XB  = Cn * XCH;              // 98304 (one batch)

__device__ __constant__ float kMops[16][4] = {
    {0, 0, 0, 0},  {0, 0, 0, 1},  {0, 1, 0, -1}, {0, 1, 0, 0},
    {0, 0, 1, -1}, {0, 0, 1, 0},  {0, 1, 1, -2}, {0, 1, 1, -1},
    {1, -1, -1, 1},{1, -1, -1, 2},{1, 0, -1, 0}, {1, 0, -1, 1},
    {1, -1, 0, 0}, {1, -1, 0, 1}, {1, 0, 0, -1}, {1, 0, 0, 0}};

__global__ __launch_bounds__(256)
void logic_conv3d(const float* __restrict__ x,
                  const int* __restrict__ idx_a,
                  const int* __restrict__ idx_b,
                  const float* __restrict__ w0,
                  const float* __restrict__ w1,
                  const float* __restrict__ w2,
                  const float* __restrict__ w3,
                  const float* __restrict__ w4,
                  float* __restrict__ out) {
    const int k = blockIdx.y;
    const int tid = threadIdx.x;

    // 31 coefficient rows (float4 -> one ds_read_b128 each):
    // lvl0 n=0..15 -> rows 0..15, lvl1 -> 16..23, lvl2 -> 24..27,
    // lvl3 -> 28..29, lvl4 -> 30.
    __shared__ float4 coef4[31];
    __shared__ int2 baseab[Sn];  // .x = base_a[s], .y = base_b[s]

    // idx_a[k, p=0, s, :] == pa[k, s] because off[0] == (0,0,0,0) (PAD=0).
    if (tid < Sn) {
        const int* pa = idx_a + (((size_t)k * Pn) * Sn + tid) * 4;
        const int* pb = idx_b + (((size_t)k * Pn) * Sn + tid) * 4;
        int2 bb;
        bb.x = pa[3] * XCH + pa[0] * (Wn * Dn) + pa[1] * Dn + pa[2];
        bb.y = pb[3] * XCH + pb[0] * (Wn * Dn) + pb[1] * Dn + pb[2];
        baseab[tid] = bb;
    }
    if (tid < 31) {
        const float* wl;
        int n;
        if (tid < 16)      { wl = w0; n = tid; }
        else if (tid < 24) { wl = w1; n = tid - 16; }
        else if (tid < 28) { wl = w2; n = tid - 24; }
        else if (tid < 30) { wl = w3; n = tid - 28; }
        else               { wl = w4; n = 0; }
        const float* row = wl + (n * Kn + k) * 16;  // w_l[n, k, :]
        float e[16];
        float mx = row[0];
        #pragma unroll
        for (int o = 1; o < 16; ++o) mx = fmaxf(mx, row[o]);
        float sum = 0.f;
        #pragma unroll
        for (int o = 0; o < 16; ++o) { e[o] = expf(row[o] - mx); sum += e[o]; }
        const float inv = 1.0f / sum;
        float4 c;
        float acc;
        acc = 0.f;
        #pragma unroll
        for (int o = 0; o < 16; ++o) acc += e[o] * kMops[o][0];
        c.x = acc * inv;
        acc = 0.f;
        #pragma unroll
        for (int o = 0; o < 16; ++o) acc += e[o] * kMops[o][1];
        c.y = acc * inv;
        acc = 0.f;
        #pragma unroll
        for (int o = 0; o < 16; ++o) acc += e[o] * kMops[o][2];
        c.z = acc * inv;
        acc = 0.f;
        #pragma unroll
        for (int o = 0; o < 16; ++o) acc += e[o] * kMops[o][3];
        c.w = acc * inv;
        coef4[tid] = c;
    }
    __syncthreads();

    const int p = blockIdx.x * blockDim.x + tid;
    if (p >= Pn) return;

    // p = h0*900 + w0*30 + d0  (meshgrid 'ij', d fastest)
    const int h0 = p / 900;
    const int rem = p - h0 * 900;
    const int w0i = rem / 30;
    const int d0 = rem - w0i * 30;
    const int poff = h0 * (Wn * Dn) + w0i * Dn + d0;

    float v[Bn][16];

    // Level 0: one coef ds_read_b128 per node, batch INNER so each coef row
    // is loaded exactly once per thread.
    #pragma unroll
    for (int s = 0; s < 16; ++s) {
        const int2 bs = baseab[s];
        const int oa = bs.x + poff;
        const int ob = bs.y + poff;
        const float4 c = coef4[s];
        #pragma unroll
        for (int b = 0; b < Bn; ++b) {
            const float a  = x[(size_t)b * XB + oa];
            const float bb = x[(size_t)b * XB + ob];
            v[b][s] = c.x + c.y * a + c.z * bb + c.w * (a * bb);
        }
    }
    #pragma unroll
    for (int n = 0; n < 8; ++n) {
        const float4 c = coef4[16 + n];
        #pragma unroll
        for (int b = 0; b < Bn; ++b) {
            const float a = v[b][2 * n], bb = v[b][2 * n + 1];
            v[b][n] = c.x + c.y * a + c.z * bb + c.w * (a * bb);
        }
    }
    #pragma unroll
    for (int n = 0; n < 4; ++n) {
        const float4 c = coef4[24 + n];
        #pragma unroll
        for (int b = 0; b < Bn; ++b) {
            const float a = v[b][2 * n], bb = v[b][2 * n + 1];
            v[b][n] = c.x + c.y * a + c.z * bb + c.w * (a * bb);
        }
    }
    #pragma unroll
    for (int n = 0; n < 2; ++n) {
        const float4 c = coef4[28 + n];
        #pragma unroll
        for (int b = 0; b < Bn; ++b) {
            const float a = v[b][2 * n], bb = v[b][2 * n + 1];
            v[b][n] = c.x + c.y * a + c.z * bb + c.w * (a * bb);
        }
    }
    {
        const float4 c = coef4[30];
        #pragma unroll
        for (int b = 0; b < Bn; ++b) {
            const float a = v[b][0], bb = v[b][1];
            const float res = c.x + c.y * a + c.z * bb + c.w * (a * bb);
            out[((size_t)b * Kn + k) * Pn + p] = res;
        }
    }
}

}  // namespace

extern "C" void kernel_launch(void* const* d_in, const int* in_sizes, int n_in,
                              void* d_out, int out_size, void* d_ws, size_t ws_size,
                              hipStream_t stream) {
    const float* x     = (const float*)d_in[0];
    const int*   idx_a = (const int*)d_in[1];
    const int*   idx_b = (const int*)d_in[2];
    const float* w0    = (const float*)d_in[3];
    const float* w1    = (const float*)d_in[4];
    const float* w2    = (const float*)d_in[5];
    const float* w3    = (const float*)d_in[6];
    const float* w4    = (const float*)d_in[7];
    float* out = (float*)d_out;

    dim3 grid((Pn + 255) / 256, Kn);
    hipLaunchKernelGGL(logic_conv3d, grid, dim3(256), 0, stream,
                       x, idx_a, idx_b, w0, w1, w2, w3, w4, out);
}